// Round 1
// baseline (1576.268 us; speedup 1.0000x reference)
//
#include <hip/hip_runtime.h>
#include <hip/hip_bf16.h>

#define D_H 128

// ---------------- degree / normalization ----------------

__global__ __launch_bounds__(256)
void deg_count_kernel(const int* __restrict__ dst, float* __restrict__ deg, int E) {
    int e = blockIdx.x * 256 + threadIdx.x;
    if (e < E) atomicAdd(&deg[dst[e]], 1.0f);
}

__global__ __launch_bounds__(256)
void dis_finalize_kernel(float* __restrict__ dis, int M) {
    int i = blockIdx.x * 256 + threadIdx.x;
    if (i < M) dis[i] = rsqrtf(dis[i] + 1.0f);
}

// ---------------- dense GEMM: Y = act(X @ W (+ b)) ----------------
// X: [M,128], W: [128,128] row-major (k,n), Y: [M,128]
// MODE 0: Y = X@W          MODE 1: Y = lrelu(X@W + b)
template<int MODE>
__global__ __launch_bounds__(512)
void gemm128_kernel(const float* __restrict__ X, const float* __restrict__ W,
                    const float* __restrict__ bias, float* __restrict__ Y, int M) {
    __shared__ float sW[128 * 128];      // [k][n]  64 KB
    __shared__ float sX[128][132];       // padded (+4 floats) to kill bank conflicts

    const int tid  = threadIdx.x;
    const int row0 = blockIdx.x * 128;

    // stage W (16384 floats = 4096 float4)
    const float4* W4  = (const float4*)W;
    float4*       sW4 = (float4*)sW;
#pragma unroll
    for (int i = 0; i < 8; ++i) sW4[tid + i * 512] = W4[tid + i * 512];

    // stage X tile (128 rows x 32 float4)
    const float4* X4 = (const float4*)X;
#pragma unroll
    for (int i = 0; i < 8; ++i) {
        int f = tid + i * 512;
        int r = f >> 5, c = f & 31;
        float4 v = make_float4(0.f, 0.f, 0.f, 0.f);
        int row = row0 + r;
        if (row < M) v = X4[(size_t)row * 32 + c];
        *(float4*)&sX[r][c * 4] = v;
    }
    __syncthreads();

    const int tc = tid & 31;   // cols tc*4 .. tc*4+3
    const int tr = tid >> 5;   // rows tr*8 .. tr*8+7

    float acc[8][4];
#pragma unroll
    for (int r = 0; r < 8; ++r)
#pragma unroll
        for (int c = 0; c < 4; ++c) acc[r][c] = 0.f;

    for (int k = 0; k < 128; k += 4) {
        float4 w0 = sW4[(k + 0) * 32 + tc];
        float4 w1 = sW4[(k + 1) * 32 + tc];
        float4 w2 = sW4[(k + 2) * 32 + tc];
        float4 w3 = sW4[(k + 3) * 32 + tc];
#pragma unroll
        for (int r = 0; r < 8; ++r) {
            float4 a = *(const float4*)&sX[tr * 8 + r][k];
            acc[r][0] += a.x * w0.x + a.y * w1.x + a.z * w2.x + a.w * w3.x;
            acc[r][1] += a.x * w0.y + a.y * w1.y + a.z * w2.y + a.w * w3.y;
            acc[r][2] += a.x * w0.z + a.y * w1.z + a.z * w2.z + a.w * w3.z;
            acc[r][3] += a.x * w0.w + a.y * w1.w + a.z * w2.w + a.w * w3.w;
        }
    }

    float4 bb = make_float4(0.f, 0.f, 0.f, 0.f);
    if (MODE == 1) bb = ((const float4*)bias)[tc];

#pragma unroll
    for (int r = 0; r < 8; ++r) {
        int row = row0 + tr * 8 + r;
        if (row < M) {
            float4 o;
            o.x = acc[r][0]; o.y = acc[r][1]; o.z = acc[r][2]; o.w = acc[r][3];
            if (MODE == 1) {
                o.x += bb.x; o.y += bb.y; o.z += bb.z; o.w += bb.w;
                o.x = o.x > 0.f ? o.x : 0.01f * o.x;
                o.y = o.y > 0.f ? o.y : 0.01f * o.y;
                o.z = o.z > 0.f ? o.z : 0.01f * o.z;
                o.w = o.w > 0.f ? o.w : 0.01f * o.w;
            }
            ((float4*)Y)[(size_t)row * 32 + tc] = o;
        }
    }
}

// ---------------- GCN pieces ----------------

// C[i][:] = H[i][:] * dis[i]^2   (self-loop term, also fully initializes C)
__global__ __launch_bounds__(256)
void self_init_kernel(const float* __restrict__ H, const float* __restrict__ dis,
                      float* __restrict__ C, int M) {
    int i = blockIdx.x * 256 + threadIdx.x;   // over M*32 float4
    if (i >= M * 32) return;
    int node = i >> 5;
    float s = dis[node]; s = s * s;
    float4 v = ((const float4*)H)[i];
    ((float4*)C)[i] = make_float4(v.x * s, v.y * s, v.z * s, v.w * s);
}

// one wave per edge: C[dst] += coef * H[src]
__global__ __launch_bounds__(256)
void gcn_agg_kernel(const float* __restrict__ H, const int* __restrict__ src,
                    const int* __restrict__ dst, const float* __restrict__ dis,
                    float* __restrict__ C, int E) {
    int w    = (blockIdx.x * 256 + threadIdx.x) >> 6;
    int lane = threadIdx.x & 63;
    if (w >= E) return;
    int s = src[w], d = dst[w];
    float coef = dis[s] * dis[d];
    float2 v = ((const float2*)H)[(size_t)s * 64 + lane];
    float* Cd = C + (size_t)d * 128 + lane * 2;
    atomicAdd(Cd,     v.x * coef);
    atomicAdd(Cd + 1, v.y * coef);
}

// Y = lrelu(C + b)
__global__ __launch_bounds__(256)
void bias_lrelu_kernel(const float* __restrict__ C, const float* __restrict__ b,
                       float* __restrict__ Y, int M) {
    int i = blockIdx.x * 256 + threadIdx.x;   // over M*32 float4
    if (i >= M * 32) return;
    int c4 = i & 31;
    float4 bb = ((const float4*)b)[c4];
    float4 v = ((const float4*)C)[i];
    v.x += bb.x; v.y += bb.y; v.z += bb.z; v.w += bb.w;
    v.x = v.x > 0.f ? v.x : 0.01f * v.x;
    v.y = v.y > 0.f ? v.y : 0.01f * v.y;
    v.z = v.z > 0.f ? v.z : 0.01f * v.z;
    v.w = v.w > 0.f ? v.w : 0.01f * v.w;
    ((float4*)Y)[i] = v;
}

// ho[i] = dot(H[i][:], Wo[:,0])   one wave per node
__global__ __launch_bounds__(256)
void dot_out_kernel(const float* __restrict__ H, const float* __restrict__ Wo,
                    float* __restrict__ ho, int M) {
    int w    = (blockIdx.x * 256 + threadIdx.x) >> 6;
    int lane = threadIdx.x & 63;
    if (w >= M) return;
    float2 v  = ((const float2*)H)[(size_t)w * 64 + lane];
    float2 wv = ((const float2*)Wo)[lane];
    float p = v.x * wv.x + v.y * wv.y;
#pragma unroll
    for (int off = 32; off > 0; off >>= 1) p += __shfl_down(p, off, 64);
    if (lane == 0) ho[w] = p;
}

// out[i] = ho[i]*dis[i]^2 + bo
__global__ __launch_bounds__(256)
void out_init_kernel(const float* __restrict__ ho, const float* __restrict__ dis,
                     const float* __restrict__ bo, float* __restrict__ out, int M) {
    int i = blockIdx.x * 256 + threadIdx.x;
    if (i < M) out[i] = ho[i] * dis[i] * dis[i] + bo[0];
}

// out[dst] += dis[src]*dis[dst]*ho[src]
__global__ __launch_bounds__(256)
void out_agg_kernel(const float* __restrict__ ho, const int* __restrict__ src,
                    const int* __restrict__ dst, const float* __restrict__ dis,
                    float* __restrict__ out, int E) {
    int e = blockIdx.x * 256 + threadIdx.x;
    if (e < E) atomicAdd(&out[dst[e]], dis[src[e]] * dis[dst[e]] * ho[src[e]]);
}

// ---------------- launch ----------------

extern "C" void kernel_launch(void* const* d_in, const int* in_sizes, int n_in,
                              void* d_out, int out_size, void* d_ws, size_t ws_size,
                              hipStream_t stream) {
    const float* x   = (const float*)d_in[0];
    const int*   ei  = (const int*)d_in[1];
    const float* W1  = (const float*)d_in[2];
    const float* b1  = (const float*)d_in[3];
    const float* W2  = (const float*)d_in[4];
    const float* b2  = (const float*)d_in[5];
    const float* W3  = (const float*)d_in[6];
    const float* b3  = (const float*)d_in[7];
    const float* Wg0 = (const float*)d_in[8];
    const float* bg0 = (const float*)d_in[9];
    const float* Wg1 = (const float*)d_in[10];
    const float* bg1 = (const float*)d_in[11];
    const float* Wo  = (const float*)d_in[12];
    const float* bo  = (const float*)d_in[13];

    const int M = in_sizes[0] / D_H;       // 100000
    const int E = in_sizes[1] / 2;         // 640000
    const int* se = ei;
    const int* de = ei + E;

    float* A   = (float*)d_ws;
    float* B   = A + (size_t)M * D_H;
    float* C   = B + (size_t)M * D_H;
    float* dis = C + (size_t)M * D_H;
    float* ho  = dis + M;

    float* out = (float*)d_out;

    const int gemm_blocks = (M + 127) / 128;
    const int elem_blocks = (M * 32 + 255) / 256;

    // degree -> dis
    hipMemsetAsync(dis, 0, M * sizeof(float), stream);
    deg_count_kernel<<<(E + 255) / 256, 256, 0, stream>>>(de, dis, E);
    dis_finalize_kernel<<<(M + 255) / 256, 256, 0, stream>>>(dis, M);

    // MLP
    gemm128_kernel<1><<<gemm_blocks, 512, 0, stream>>>(x, W1, b1, A, M);
    gemm128_kernel<1><<<gemm_blocks, 512, 0, stream>>>(A, W2, b2, B, M);
    gemm128_kernel<1><<<gemm_blocks, 512, 0, stream>>>(B, W3, b3, A, M);

    // GCN 0
    gemm128_kernel<0><<<gemm_blocks, 512, 0, stream>>>(A, Wg0, nullptr, B, M);
    self_init_kernel<<<elem_blocks, 256, 0, stream>>>(B, dis, C, M);
    gcn_agg_kernel<<<(E * 64 + 255) / 256, 256, 0, stream>>>(B, se, de, dis, C, E);
    bias_lrelu_kernel<<<elem_blocks, 256, 0, stream>>>(C, bg0, A, M);

    // GCN 1
    gemm128_kernel<0><<<gemm_blocks, 512, 0, stream>>>(A, Wg1, nullptr, B, M);
    self_init_kernel<<<elem_blocks, 256, 0, stream>>>(B, dis, C, M);
    gcn_agg_kernel<<<(E * 64 + 255) / 256, 256, 0, stream>>>(B, se, de, dis, C, E);
    bias_lrelu_kernel<<<elem_blocks, 256, 0, stream>>>(C, bg1, A, M);

    // GCN 2 (128 -> 1)
    dot_out_kernel<<<(M * 64 + 255) / 256, 256, 0, stream>>>(A, Wo, ho, M);
    out_init_kernel<<<(M + 255) / 256, 256, 0, stream>>>(ho, dis, bo, out, M);
    out_agg_kernel<<<(E + 255) / 256, 256, 0, stream>>>(ho, se, de, dis, out, E);
}

// Round 2
// 600.420 us; speedup vs baseline: 2.6253x; 2.6253x over previous
//
#include <hip/hip_runtime.h>
#include <hip/hip_bf16.h>

#define D_H 128

// ================= CSR build =================

__global__ __launch_bounds__(256)
void deg_count_int_kernel(const int* __restrict__ dst, int* __restrict__ cnt, int E) {
    int e = blockIdx.x * 256 + threadIdx.x;
    if (e < E) atomicAdd(&cnt[dst[e]], 1);
}

// dis[i] = rsqrt(deg_i + 1)
__global__ __launch_bounds__(256)
void dis_finalize_kernel(const int* __restrict__ cnt, float* __restrict__ dis, int M) {
    int i = blockIdx.x * 256 + threadIdx.x;
    if (i < M) dis[i] = rsqrtf((float)cnt[i] + 1.0f);
}

// each block scans a 1024-chunk of cnt -> exclusive positions in rowptr, chunk total -> aux
__global__ __launch_bounds__(256)
void scan_blocks_kernel(const int* __restrict__ cnt, int* __restrict__ rowptr,
                        int* __restrict__ aux, int M) {
    __shared__ int sdata[256];
    const int base = blockIdx.x * 1024 + threadIdx.x * 4;
    int v[4];
#pragma unroll
    for (int i = 0; i < 4; ++i) v[i] = (base + i < M) ? cnt[base + i] : 0;
    int tsum = v[0] + v[1] + v[2] + v[3];
    sdata[threadIdx.x] = tsum;
    __syncthreads();
    int val = tsum;
    for (int off = 1; off < 256; off <<= 1) {
        int n = (threadIdx.x >= off) ? sdata[threadIdx.x - off] : 0;
        __syncthreads();
        val += n;
        sdata[threadIdx.x] = val;
        __syncthreads();
    }
    int run = val - tsum;  // exclusive prefix of this thread within chunk
#pragma unroll
    for (int i = 0; i < 4; ++i) {
        if (base + i < M) rowptr[base + i] = run;
        run += v[i];
    }
    if (threadIdx.x == 255) aux[blockIdx.x] = val;  // chunk total
}

// single block: exclusive scan of chunk totals (nChunks <= 128)
__global__ __launch_bounds__(128)
void scan_aux_kernel(int* __restrict__ aux, int n) {
    __shared__ int s[128];
    int v = (threadIdx.x < n) ? aux[threadIdx.x] : 0;
    s[threadIdx.x] = v;
    __syncthreads();
    int val = v;
    for (int off = 1; off < 128; off <<= 1) {
        int nn = (threadIdx.x >= off) ? s[threadIdx.x - off] : 0;
        __syncthreads();
        val += nn;
        s[threadIdx.x] = val;
        __syncthreads();
    }
    if (threadIdx.x < n) aux[threadIdx.x] = val - v;
}

__global__ __launch_bounds__(256)
void scan_add_kernel(int* __restrict__ rowptr, int* __restrict__ cursor,
                     const int* __restrict__ aux, int M) {
    int i = blockIdx.x * 256 + threadIdx.x;
    if (i >= M) return;
    int v = rowptr[i] + aux[i >> 10];
    rowptr[i] = v;
    cursor[i] = v;
}

// dst-sorted edge arrays: es[pos]=src, ces[pos]=dis[src]
__global__ __launch_bounds__(256)
void scatter_kernel(const int* __restrict__ src, const int* __restrict__ dst,
                    const float* __restrict__ dis, int* __restrict__ cursor,
                    int* __restrict__ es, float* __restrict__ ces, int E) {
    int e = blockIdx.x * 256 + threadIdx.x;
    if (e >= E) return;
    int s = src[e], d = dst[e];
    int pos = atomicAdd(&cursor[d], 1);
    es[pos] = s;
    ces[pos] = dis[s];
}

// ================= dense GEMM: Y = act(X @ W (+ b)) =================
template<int MODE>  // 0: X@W   1: lrelu(X@W + b)
__global__ __launch_bounds__(512)
void gemm128_kernel(const float* __restrict__ X, const float* __restrict__ W,
                    const float* __restrict__ bias, float* __restrict__ Y, int M) {
    __shared__ float sW[128 * 128];
    __shared__ float sX[128][132];

    const int tid  = threadIdx.x;
    const int row0 = blockIdx.x * 128;

    const float4* W4  = (const float4*)W;
    float4*       sW4 = (float4*)sW;
#pragma unroll
    for (int i = 0; i < 8; ++i) sW4[tid + i * 512] = W4[tid + i * 512];

    const float4* X4 = (const float4*)X;
#pragma unroll
    for (int i = 0; i < 8; ++i) {
        int f = tid + i * 512;
        int r = f >> 5, c = f & 31;
        float4 v = make_float4(0.f, 0.f, 0.f, 0.f);
        int row = row0 + r;
        if (row < M) v = X4[(size_t)row * 32 + c];
        *(float4*)&sX[r][c * 4] = v;
    }
    __syncthreads();

    const int tc = tid & 31;
    const int tr = tid >> 5;

    float acc[8][4];
#pragma unroll
    for (int r = 0; r < 8; ++r)
#pragma unroll
        for (int c = 0; c < 4; ++c) acc[r][c] = 0.f;

    for (int k = 0; k < 128; k += 4) {
        float4 w0 = sW4[(k + 0) * 32 + tc];
        float4 w1 = sW4[(k + 1) * 32 + tc];
        float4 w2 = sW4[(k + 2) * 32 + tc];
        float4 w3 = sW4[(k + 3) * 32 + tc];
#pragma unroll
        for (int r = 0; r < 8; ++r) {
            float4 a = *(const float4*)&sX[tr * 8 + r][k];
            acc[r][0] += a.x * w0.x + a.y * w1.x + a.z * w2.x + a.w * w3.x;
            acc[r][1] += a.x * w0.y + a.y * w1.y + a.z * w2.y + a.w * w3.y;
            acc[r][2] += a.x * w0.z + a.y * w1.z + a.z * w2.z + a.w * w3.z;
            acc[r][3] += a.x * w0.w + a.y * w1.w + a.z * w2.w + a.w * w3.w;
        }
    }

    float4 bb = make_float4(0.f, 0.f, 0.f, 0.f);
    if (MODE == 1) bb = ((const float4*)bias)[tc];

#pragma unroll
    for (int r = 0; r < 8; ++r) {
        int row = row0 + tr * 8 + r;
        if (row < M) {
            float4 o;
            o.x = acc[r][0]; o.y = acc[r][1]; o.z = acc[r][2]; o.w = acc[r][3];
            if (MODE == 1) {
                o.x += bb.x; o.y += bb.y; o.z += bb.z; o.w += bb.w;
                o.x = o.x > 0.f ? o.x : 0.01f * o.x;
                o.y = o.y > 0.f ? o.y : 0.01f * o.y;
                o.z = o.z > 0.f ? o.z : 0.01f * o.z;
                o.w = o.w > 0.f ? o.w : 0.01f * o.w;
            }
            ((float4*)Y)[(size_t)row * 32 + tc] = o;
        }
    }
}

// ================= fused GCN aggregation (CSR, no atomics) =================
// one wave per node: Y[d] = lrelu( dis_d^2*H[d] + sum_j ces[j]*dis_d*H[es[j]] + b )
__global__ __launch_bounds__(256)
void gcn_agg_csr_kernel(const float* __restrict__ H, const int* __restrict__ es,
                        const float* __restrict__ ces, const int* __restrict__ rowptr,
                        const int* __restrict__ cnt, const float* __restrict__ dis,
                        const float* __restrict__ bias, float* __restrict__ Y, int M) {
    int w    = (blockIdx.x * 256 + threadIdx.x) >> 6;
    int lane = threadIdx.x & 63;
    if (w >= M) return;

    const float dd  = dis[w];
    const int   beg = rowptr[w];
    const int   n   = cnt[w];

    float2 hv = ((const float2*)H)[(size_t)w * 64 + lane];
    float2 acc;
    acc.x = hv.x * dd * dd;
    acc.y = hv.y * dd * dd;

    int j = 0;
    for (; j + 4 <= n; j += 4) {
        int   s0 = es[beg + j],      s1 = es[beg + j + 1];
        int   s2 = es[beg + j + 2],  s3 = es[beg + j + 3];
        float c0 = ces[beg + j] * dd,     c1 = ces[beg + j + 1] * dd;
        float c2 = ces[beg + j + 2] * dd, c3 = ces[beg + j + 3] * dd;
        float2 v0 = ((const float2*)H)[(size_t)s0 * 64 + lane];
        float2 v1 = ((const float2*)H)[(size_t)s1 * 64 + lane];
        float2 v2 = ((const float2*)H)[(size_t)s2 * 64 + lane];
        float2 v3 = ((const float2*)H)[(size_t)s3 * 64 + lane];
        acc.x += c0 * v0.x + c1 * v1.x + c2 * v2.x + c3 * v3.x;
        acc.y += c0 * v0.y + c1 * v1.y + c2 * v2.y + c3 * v3.y;
    }
    for (; j < n; ++j) {
        int   s = es[beg + j];
        float c = ces[beg + j] * dd;
        float2 v = ((const float2*)H)[(size_t)s * 64 + lane];
        acc.x += c * v.x;
        acc.y += c * v.y;
    }

    float2 bb = ((const float2*)bias)[lane];
    acc.x += bb.x; acc.y += bb.y;
    acc.x = acc.x > 0.f ? acc.x : 0.01f * acc.x;
    acc.y = acc.y > 0.f ? acc.y : 0.01f * acc.y;
    ((float2*)Y)[(size_t)w * 64 + lane] = acc;
}

// ================= output layer =================

// ho[i] = dot(H[i][:], Wo[:,0])   one wave per node
__global__ __launch_bounds__(256)
void dot_out_kernel(const float* __restrict__ H, const float* __restrict__ Wo,
                    float* __restrict__ ho, int M) {
    int w    = (blockIdx.x * 256 + threadIdx.x) >> 6;
    int lane = threadIdx.x & 63;
    if (w >= M) return;
    float2 v  = ((const float2*)H)[(size_t)w * 64 + lane];
    float2 wv = ((const float2*)Wo)[lane];
    float p = v.x * wv.x + v.y * wv.y;
#pragma unroll
    for (int off = 32; off > 0; off >>= 1) p += __shfl_down(p, off, 64);
    if (lane == 0) ho[w] = p;
}

// out[i] = bo + dis_i^2*ho[i] + sum_j ces[j]*dis_i*ho[es[j]]   (one thread/node)
__global__ __launch_bounds__(256)
void out_csr_kernel(const float* __restrict__ ho, const int* __restrict__ es,
                    const float* __restrict__ ces, const int* __restrict__ rowptr,
                    const int* __restrict__ cnt, const float* __restrict__ dis,
                    const float* __restrict__ bo, float* __restrict__ out, int M) {
    int i = blockIdx.x * 256 + threadIdx.x;
    if (i >= M) return;
    float dd  = dis[i];
    float acc = ho[i] * dd * dd;
    int   beg = rowptr[i], n = cnt[i];
    for (int j = 0; j < n; ++j)
        acc += ces[beg + j] * dd * ho[es[beg + j]];
    out[i] = acc + bo[0];
}

// ================= launch =================

extern "C" void kernel_launch(void* const* d_in, const int* in_sizes, int n_in,
                              void* d_out, int out_size, void* d_ws, size_t ws_size,
                              hipStream_t stream) {
    const float* x   = (const float*)d_in[0];
    const int*   ei  = (const int*)d_in[1];
    const float* W1  = (const float*)d_in[2];
    const float* b1  = (const float*)d_in[3];
    const float* W2  = (const float*)d_in[4];
    const float* b2  = (const float*)d_in[5];
    const float* W3  = (const float*)d_in[6];
    const float* b3  = (const float*)d_in[7];
    const float* Wg0 = (const float*)d_in[8];
    const float* bg0 = (const float*)d_in[9];
    const float* Wg1 = (const float*)d_in[10];
    const float* bg1 = (const float*)d_in[11];
    const float* Wo  = (const float*)d_in[12];
    const float* bo  = (const float*)d_in[13];

    const int M = in_sizes[0] / D_H;   // 100000
    const int E = in_sizes[1] / 2;     // 640000
    const int* se = ei;
    const int* de = ei + E;

    // workspace layout (floats/ints, all 4-byte)
    float* A      = (float*)d_ws;                    // [M*128]
    float* B      = A + (size_t)M * D_H;             // [M*128]
    float* dis    = B + (size_t)M * D_H;             // [M]
    float* ho     = dis + M;                         // [M]
    float* ces    = ho + M;                          // [E]
    int*   cnt    = (int*)(ces + E);                 // [M]
    int*   rowptr = cnt + M;                         // [M]
    int*   cursor = rowptr + M;                      // [M]
    int*   es     = cursor + M;                      // [E]
    int*   aux    = es + E;                          // [128]

    float* out = (float*)d_out;

    const int nChunks     = (M + 1023) / 1024;
    const int gemm_blocks = (M + 127) / 128;
    const int node_waves  = (M * 64 + 255) / 256;

    // ---- CSR build ----
    hipMemsetAsync(cnt, 0, M * sizeof(int), stream);
    deg_count_int_kernel<<<(E + 255) / 256, 256, 0, stream>>>(de, cnt, E);
    scan_blocks_kernel<<<nChunks, 256, 0, stream>>>(cnt, rowptr, aux, M);
    scan_aux_kernel<<<1, 128, 0, stream>>>(aux, nChunks);
    scan_add_kernel<<<(M + 255) / 256, 256, 0, stream>>>(rowptr, cursor, aux, M);
    dis_finalize_kernel<<<(M + 255) / 256, 256, 0, stream>>>(cnt, dis, M);
    scatter_kernel<<<(E + 255) / 256, 256, 0, stream>>>(se, de, dis, cursor, es, ces, E);

    // ---- MLP ----
    gemm128_kernel<1><<<gemm_blocks, 512, 0, stream>>>(x, W1, b1, A, M);
    gemm128_kernel<1><<<gemm_blocks, 512, 0, stream>>>(A, W2, b2, B, M);
    gemm128_kernel<1><<<gemm_blocks, 512, 0, stream>>>(B, W3, b3, A, M);

    // ---- GCN 0 ----
    gemm128_kernel<0><<<gemm_blocks, 512, 0, stream>>>(A, Wg0, nullptr, B, M);
    gcn_agg_csr_kernel<<<node_waves, 256, 0, stream>>>(B, es, ces, rowptr, cnt, dis, bg0, A, M);

    // ---- GCN 1 ----
    gemm128_kernel<0><<<gemm_blocks, 512, 0, stream>>>(A, Wg1, nullptr, B, M);
    gcn_agg_csr_kernel<<<node_waves, 256, 0, stream>>>(B, es, ces, rowptr, cnt, dis, bg1, A, M);

    // ---- GCN 2 (128 -> 1) ----
    dot_out_kernel<<<node_waves, 256, 0, stream>>>(A, Wo, ho, M);
    out_csr_kernel<<<(M + 255) / 256, 256, 0, stream>>>(ho, es, ces, rowptr, cnt, dis, bo, out, M);
}

// Round 3
// 363.767 us; speedup vs baseline: 4.3332x; 1.6506x over previous
//
#include <hip/hip_runtime.h>
#include <hip/hip_bf16.h>

#define D_H 128

typedef __attribute__((ext_vector_type(8))) short bf16x8;
typedef __attribute__((ext_vector_type(4))) float f32x4;

__device__ inline ushort f2bf_bits(float x) {
    __hip_bfloat16 b = __float2bfloat16(x);
    return *reinterpret_cast<ushort*>(&b);
}
__device__ inline float bf_bits2f(ushort u) {
    __hip_bfloat16 b = *reinterpret_cast<__hip_bfloat16*>(&u);
    return __bfloat162float(b);
}

// ================= CSR build =================

__global__ __launch_bounds__(256)
void deg_count_int_kernel(const int* __restrict__ dst, int* __restrict__ cnt, int E) {
    int e = blockIdx.x * 256 + threadIdx.x;
    if (e < E) atomicAdd(&cnt[dst[e]], 1);
}

__global__ __launch_bounds__(256)
void dis_finalize_kernel(const int* __restrict__ cnt, float* __restrict__ dis, int M) {
    int i = blockIdx.x * 256 + threadIdx.x;
    if (i < M) dis[i] = rsqrtf((float)cnt[i] + 1.0f);
}

__global__ __launch_bounds__(256)
void scan_blocks_kernel(const int* __restrict__ cnt, int* __restrict__ rowptr,
                        int* __restrict__ aux, int M) {
    __shared__ int sdata[256];
    const int base = blockIdx.x * 1024 + threadIdx.x * 4;
    int v[4];
#pragma unroll
    for (int i = 0; i < 4; ++i) v[i] = (base + i < M) ? cnt[base + i] : 0;
    int tsum = v[0] + v[1] + v[2] + v[3];
    sdata[threadIdx.x] = tsum;
    __syncthreads();
    int val = tsum;
    for (int off = 1; off < 256; off <<= 1) {
        int n = (threadIdx.x >= off) ? sdata[threadIdx.x - off] : 0;
        __syncthreads();
        val += n;
        sdata[threadIdx.x] = val;
        __syncthreads();
    }
    int run = val - tsum;
#pragma unroll
    for (int i = 0; i < 4; ++i) {
        if (base + i < M) rowptr[base + i] = run;
        run += v[i];
    }
    if (threadIdx.x == 255) aux[blockIdx.x] = val;
}

__global__ __launch_bounds__(128)
void scan_aux_kernel(int* __restrict__ aux, int n) {
    __shared__ int s[128];
    int v = (threadIdx.x < n) ? aux[threadIdx.x] : 0;
    s[threadIdx.x] = v;
    __syncthreads();
    int val = v;
    for (int off = 1; off < 128; off <<= 1) {
        int nn = (threadIdx.x >= off) ? s[threadIdx.x - off] : 0;
        __syncthreads();
        val += nn;
        s[threadIdx.x] = val;
        __syncthreads();
    }
    if (threadIdx.x < n) aux[threadIdx.x] = val - v;
}

__global__ __launch_bounds__(256)
void scan_add_kernel(int* __restrict__ rowptr, int* __restrict__ cursor,
                     const int* __restrict__ aux, int M) {
    int i = blockIdx.x * 256 + threadIdx.x;
    if (i >= M) return;
    int v = rowptr[i] + aux[i >> 10];
    rowptr[i] = v;
    cursor[i] = v;
}

__global__ __launch_bounds__(256)
void scatter_kernel(const int* __restrict__ src, const int* __restrict__ dst,
                    const float* __restrict__ dis, int* __restrict__ cursor,
                    int* __restrict__ es, float* __restrict__ ces, int E) {
    int e = blockIdx.x * 256 + threadIdx.x;
    if (e >= E) return;
    int s = src[e], d = dst[e];
    int pos = atomicAdd(&cursor[d], 1);
    es[pos] = s;
    ces[pos] = dis[s];
}

// ================= weight prep: W[k][n] fp32 -> hi/lo bf16 image [n][136] =================
// per weight image: 17408 ushorts hi, then 17408 ushorts lo (34816 ushorts = 69632 B)
__global__ __launch_bounds__(256)
void wprep_kernel(const float* __restrict__ W1, const float* __restrict__ W2,
                  const float* __restrict__ W3, const float* __restrict__ W4,
                  const float* __restrict__ W5, ushort* __restrict__ imgs) {
    int w = blockIdx.x >> 6;                 // 0..4
    int e = (blockIdx.x & 63) * 256 + threadIdx.x;  // 0..16383
    const float* W = w == 0 ? W1 : w == 1 ? W2 : w == 2 ? W3 : w == 3 ? W4 : W5;
    int k = e >> 7, n = e & 127;
    float a  = W[e];
    ushort hi = f2bf_bits(a);
    ushort lo = f2bf_bits(a - bf_bits2f(hi));
    ushort* img = imgs + (size_t)w * 34816;
    img[n * 136 + k]         = hi;
    img[17408 + n * 136 + k] = lo;
}

// ================= MFMA GEMM: Y = act(X @ W (+ b)) =================
// X:[M,128] fp32, Wimg: hi/lo bf16 [n][136], Y:[M,128] fp32
// block: 128 rows, 8 waves x 16 rows; full N=128, K=128
template<int MODE>  // 0: X@W   1: lrelu(X@W + b)
__global__ __launch_bounds__(512)
void gemm128_mfma_kernel(const float* __restrict__ X, const ushort* __restrict__ img,
                         const float* __restrict__ bias, float* __restrict__ Y, int M) {
    __shared__ ushort sB[34816];   // hi [128][136], lo [128][136]  (69632 B)

    const int tid  = threadIdx.x;
    const int lane = tid & 63;
    const int wv   = tid >> 6;
    const int row0 = blockIdx.x * 128 + wv * 16;

    // ---- stage W image (linear, coalesced 16B) ----
    {
        const uint4* g4 = (const uint4*)img;
        uint4*       s4 = (uint4*)sB;
#pragma unroll
        for (int j = 0; j < 9; ++j) {
            int c = j * 512 + tid;
            if (c < 4352) s4[c] = g4[c];
        }
    }

    // ---- load + convert A fragments (no LDS round-trip) ----
    const int arow = row0 + (lane & 15);
    const int kof  = (lane >> 4) * 8;
    bf16x8 ahi[4], alo[4];
    {
        const bool ok = arow < M;
        const float* ap = X + (size_t)arow * 128 + kof;
#pragma unroll
        for (int kb = 0; kb < 4; ++kb) {
            float f[8];
            if (ok) {
                float4 f0 = *(const float4*)(ap + kb * 32);
                float4 f1 = *(const float4*)(ap + kb * 32 + 4);
                f[0] = f0.x; f[1] = f0.y; f[2] = f0.z; f[3] = f0.w;
                f[4] = f1.x; f[5] = f1.y; f[6] = f1.z; f[7] = f1.w;
            } else {
#pragma unroll
                for (int e = 0; e < 8; ++e) f[e] = 0.f;
            }
            bf16x8 h, l;
#pragma unroll
            for (int e = 0; e < 8; ++e) {
                ushort hb = f2bf_bits(f[e]);
                h[e] = (short)hb;
                l[e] = (short)f2bf_bits(f[e] - bf_bits2f(hb));
            }
            ahi[kb] = h; alo[kb] = l;
        }
    }
    __syncthreads();

    // ---- MFMA main: acc[nt] over 8 N-tiles, K=128, 3-term split ----
    f32x4 acc[8];
#pragma unroll
    for (int nt = 0; nt < 8; ++nt) acc[nt] = (f32x4){0.f, 0.f, 0.f, 0.f};

    const int bn = lane & 15;
#pragma unroll
    for (int kb = 0; kb < 4; ++kb) {
#pragma unroll
        for (int nt = 0; nt < 8; ++nt) {
            const ushort* ph = &sB[(nt * 16 + bn) * 136 + kb * 32 + kof];
            bf16x8 bh = *(const bf16x8*)ph;
            bf16x8 bl = *(const bf16x8*)(ph + 17408);
            acc[nt] = __builtin_amdgcn_mfma_f32_16x16x32_bf16(ahi[kb], bh, acc[nt], 0, 0, 0);
            acc[nt] = __builtin_amdgcn_mfma_f32_16x16x32_bf16(alo[kb], bh, acc[nt], 0, 0, 0);
            acc[nt] = __builtin_amdgcn_mfma_f32_16x16x32_bf16(ahi[kb], bl, acc[nt], 0, 0, 0);
        }
    }

    // ---- epilogue: C/D layout col=lane&15, row=(lane>>4)*4+i ----
    const int orow0 = row0 + (lane >> 4) * 4;
#pragma unroll
    for (int nt = 0; nt < 8; ++nt) {
        int col = nt * 16 + bn;
        float bcol = 0.f;
        if (MODE == 1) bcol = bias[col];
#pragma unroll
        for (int i = 0; i < 4; ++i) {
            int row = orow0 + i;
            if (row < M) {
                float v = acc[nt][i];
                if (MODE == 1) { v += bcol; v = v > 0.f ? v : 0.01f * v; }
                Y[(size_t)row * 128 + col] = v;
            }
        }
    }
}

// ================= fused GCN aggregation (CSR, no atomics) =================
__global__ __launch_bounds__(256)
void gcn_agg_csr_kernel(const float* __restrict__ H, const int* __restrict__ es,
                        const float* __restrict__ ces, const int* __restrict__ rowptr,
                        const int* __restrict__ cnt, const float* __restrict__ dis,
                        const float* __restrict__ bias, float* __restrict__ Y, int M) {
    int w    = (blockIdx.x * 256 + threadIdx.x) >> 6;
    int lane = threadIdx.x & 63;
    if (w >= M) return;

    const float dd  = dis[w];
    const int   beg = rowptr[w];
    const int   n   = cnt[w];

    float2 hv = ((const float2*)H)[(size_t)w * 64 + lane];
    float2 acc;
    acc.x = hv.x * dd * dd;
    acc.y = hv.y * dd * dd;

    int j = 0;
    for (; j + 4 <= n; j += 4) {
        int   s0 = es[beg + j],      s1 = es[beg + j + 1];
        int   s2 = es[beg + j + 2],  s3 = es[beg + j + 3];
        float c0 = ces[beg + j] * dd,     c1 = ces[beg + j + 1] * dd;
        float c2 = ces[beg + j + 2] * dd, c3 = ces[beg + j + 3] * dd;
        float2 v0 = ((const float2*)H)[(size_t)s0 * 64 + lane];
        float2 v1 = ((const float2*)H)[(size_t)s1 * 64 + lane];
        float2 v2 = ((const float2*)H)[(size_t)s2 * 64 + lane];
        float2 v3 = ((const float2*)H)[(size_t)s3 * 64 + lane];
        acc.x += c0 * v0.x + c1 * v1.x + c2 * v2.x + c3 * v3.x;
        acc.y += c0 * v0.y + c1 * v1.y + c2 * v2.y + c3 * v3.y;
    }
    for (; j < n; ++j) {
        int   s = es[beg + j];
        float c = ces[beg + j] * dd;
        float2 v = ((const float2*)H)[(size_t)s * 64 + lane];
        acc.x += c * v.x;
        acc.y += c * v.y;
    }

    float2 bb = ((const float2*)bias)[lane];
    acc.x += bb.x; acc.y += bb.y;
    acc.x = acc.x > 0.f ? acc.x : 0.01f * acc.x;
    acc.y = acc.y > 0.f ? acc.y : 0.01f * acc.y;
    ((float2*)Y)[(size_t)w * 64 + lane] = acc;
}

// ================= output layer =================

__global__ __launch_bounds__(256)
void dot_out_kernel(const float* __restrict__ H, const float* __restrict__ Wo,
                    float* __restrict__ ho, int M) {
    int w    = (blockIdx.x * 256 + threadIdx.x) >> 6;
    int lane = threadIdx.x & 63;
    if (w >= M) return;
    float2 v  = ((const float2*)H)[(size_t)w * 64 + lane];
    float2 wv = ((const float2*)Wo)[lane];
    float p = v.x * wv.x + v.y * wv.y;
#pragma unroll
    for (int off = 32; off > 0; off >>= 1) p += __shfl_down(p, off, 64);
    if (lane == 0) ho[w] = p;
}

__global__ __launch_bounds__(256)
void out_csr_kernel(const float* __restrict__ ho, const int* __restrict__ es,
                    const float* __restrict__ ces, const int* __restrict__ rowptr,
                    const int* __restrict__ cnt, const float* __restrict__ dis,
                    const float* __restrict__ bo, float* __restrict__ out, int M) {
    int i = blockIdx.x * 256 + threadIdx.x;
    if (i >= M) return;
    float dd  = dis[i];
    float acc = ho[i] * dd * dd;
    int   beg = rowptr[i], n = cnt[i];
    for (int j = 0; j < n; ++j)
        acc += ces[beg + j] * dd * ho[es[beg + j]];
    out[i] = acc + bo[0];
}

// ================= launch =================

extern "C" void kernel_launch(void* const* d_in, const int* in_sizes, int n_in,
                              void* d_out, int out_size, void* d_ws, size_t ws_size,
                              hipStream_t stream) {
    const float* x   = (const float*)d_in[0];
    const int*   ei  = (const int*)d_in[1];
    const float* W1  = (const float*)d_in[2];
    const float* b1  = (const float*)d_in[3];
    const float* W2  = (const float*)d_in[4];
    const float* b2  = (const float*)d_in[5];
    const float* W3  = (const float*)d_in[6];
    const float* b3  = (const float*)d_in[7];
    const float* Wg0 = (const float*)d_in[8];
    const float* bg0 = (const float*)d_in[9];
    const float* Wg1 = (const float*)d_in[10];
    const float* bg1 = (const float*)d_in[11];
    const float* Wo  = (const float*)d_in[12];
    const float* bo  = (const float*)d_in[13];

    const int M = in_sizes[0] / D_H;   // 100000
    const int E = in_sizes[1] / 2;     // 640000
    const int* se = ei;
    const int* de = ei + E;

    // workspace layout
    float*  A      = (float*)d_ws;                   // [M*128]
    float*  B      = A + (size_t)M * D_H;            // [M*128]
    ushort* Wimg   = (ushort*)(B + (size_t)M * D_H); // 5 * 34816 ushorts
    float*  dis    = (float*)(Wimg + 5 * 34816);     // [M]
    float*  ho     = dis + M;                        // [M]
    float*  ces    = ho + M;                         // [E]
    int*    cnt    = (int*)(ces + E);                // [M]
    int*    rowptr = cnt + M;                        // [M]
    int*    cursor = rowptr + M;                     // [M]
    int*    es     = cursor + M;                     // [E]
    int*    aux    = es + E;                         // [128]

    float* out = (float*)d_out;

    const int nChunks     = (M + 1023) / 1024;
    const int gemm_blocks = (M + 127) / 128;
    const int node_waves  = (M * 64 + 255) / 256;

    // ---- CSR build + weight prep ----
    hipMemsetAsync(cnt, 0, M * sizeof(int), stream);
    wprep_kernel<<<320, 256, 0, stream>>>(W1, W2, W3, Wg0, Wg1, Wimg);
    deg_count_int_kernel<<<(E + 255) / 256, 256, 0, stream>>>(de, cnt, E);
    scan_blocks_kernel<<<nChunks, 256, 0, stream>>>(cnt, rowptr, aux, M);
    scan_aux_kernel<<<1, 128, 0, stream>>>(aux, nChunks);
    scan_add_kernel<<<(M + 255) / 256, 256, 0, stream>>>(rowptr, cursor, aux, M);
    dis_finalize_kernel<<<(M + 255) / 256, 256, 0, stream>>>(cnt, dis, M);
    scatter_kernel<<<(E + 255) / 256, 256, 0, stream>>>(se, de, dis, cursor, es, ces, E);

    // ---- MLP ----
    gemm128_mfma_kernel<1><<<gemm_blocks, 512, 0, stream>>>(x, Wimg + 0 * 34816, b1, A, M);
    gemm128_mfma_kernel<1><<<gemm_blocks, 512, 0, stream>>>(A, Wimg + 1 * 34816, b2, B, M);
    gemm128_mfma_kernel<1><<<gemm_blocks, 512, 0, stream>>>(B, Wimg + 2 * 34816, b3, A, M);

    // ---- GCN 0 ----
    gemm128_mfma_kernel<0><<<gemm_blocks, 512, 0, stream>>>(A, Wimg + 3 * 34816, nullptr, B, M);
    gcn_agg_csr_kernel<<<node_waves, 256, 0, stream>>>(B, es, ces, rowptr, cnt, dis, bg0, A, M);

    // ---- GCN 1 ----
    gemm128_mfma_kernel<0><<<gemm_blocks, 512, 0, stream>>>(A, Wimg + 4 * 34816, nullptr, B, M);
    gcn_agg_csr_kernel<<<node_waves, 256, 0, stream>>>(B, es, ces, rowptr, cnt, dis, bg1, A, M);

    // ---- GCN 2 (128 -> 1) ----
    dot_out_kernel<<<node_waves, 256, 0, stream>>>(A, Wo, ho, M);
    out_csr_kernel<<<(M + 255) / 256, 256, 0, stream>>>(ho, es, ces, rowptr, cnt, dis, bo, out, M);
}